// Round 8
// baseline (602.598 us; speedup 1.0000x reference)
//
#include <hip/hip_runtime.h>

// ---------------------------------------------------------------------------
// Att2in2Core: B=256, S=49, H=2048, V_SZ=10000
// fc_* / v_g are dead code in the reference; alpha_b is softmax-invariant.
// R7 decision: abandon 256^2 1-block/CU 8-phase (stuck at 23-25% MfmaUtil);
// return to m97 128^2 structure (5 blocks/CU implicit overlap) with the
// VERIFIED conflict-free XOR swizzle (pre-swizzled gload_lds source + XOR'd
// ds_read cols; SQ_LDS_BANK_CONFLICT=0 in R3-R6, refcheck'd).
// ---------------------------------------------------------------------------

typedef __bf16 bf16x8 __attribute__((ext_vector_type(8)));
typedef float  f32x4  __attribute__((ext_vector_type(4)));

static constexpr int Bn = 256;
static constexpr int Sn = 49;
static constexpr int Hn = 2048;
static constexpr int Mrows = Bn * Sn;      // 12544
static constexpr int LDP = 72;             // padded LDS stride (f32-B GEMMs)

__device__ __forceinline__ unsigned short f2bf(float f) {
    unsigned u = __builtin_bit_cast(unsigned, f);
    u += 0x7FFFu + ((u >> 16) & 1u);       // round-to-nearest-even
    return (unsigned short)(u >> 16);
}
__device__ __forceinline__ float bf2f(unsigned short h) {
    return __builtin_bit_cast(float, ((unsigned)h) << 16);
}

// -------------------- fused f32 -> bf16 convert of V, att_W, ctx_W ---------
__global__ void k_convert3(const float* __restrict__ s0, unsigned short* __restrict__ d0, int n0,
                           const float* __restrict__ s1, unsigned short* __restrict__ d1, int n1,
                           const float* __restrict__ s2, unsigned short* __restrict__ d2, int n2) {
    int i = blockIdx.x * blockDim.x + threadIdx.x;   // unit = 8 elems
    const float* src; unsigned short* dst;
    if (i < n0)            { src = s0; dst = d0; }
    else if (i < n0 + n1)  { src = s1; dst = d1; i -= n0; }
    else if (i < n0 + n1 + n2) { src = s2; dst = d2; i -= n0 + n1; }
    else return;
    const float4* p = (const float4*)src + (size_t)i * 2;
    float4 a = p[0], b = p[1];
    union { unsigned short us[8]; int4 v; } o;
    o.us[0] = f2bf(a.x); o.us[1] = f2bf(a.y); o.us[2] = f2bf(a.z); o.us[3] = f2bf(a.w);
    o.us[4] = f2bf(b.x); o.us[5] = f2bf(b.y); o.us[6] = f2bf(b.z); o.us[7] = f2bf(b.w);
    ((int4*)dst)[i] = o.v;
}

// -------------------- gather xt = relu(emb[captions[:,t]]), h_prev ----------
__global__ void k_gather(const float* __restrict__ emb,
                         const float* __restrict__ state,
                         const int* __restrict__ captions,
                         const int* __restrict__ timep,
                         unsigned short* __restrict__ xt_b,
                         unsigned short* __restrict__ h_b) {
    int b = blockIdx.x;
    int tm = timep[0];
    int it = captions[b * 16 + tm];
    const float* erow = emb + (size_t)it * Hn;
    for (int h = threadIdx.x; h < Hn; h += blockDim.x) {
        float x = erow[h];
        xt_b[(size_t)b * Hn + h] = f2bf(x > 0.f ? x : 0.f);
        float hv = (tm == 0) ? 0.f : state[(size_t)b * Hn + h];  // state[0,0,b,:]
        h_b[(size_t)b * Hn + h] = f2bf(hv);
    }
}

// ==================== FAST 128^2 GEMM (m97 structure + swizzle) =============
// C = A @ B^T. A,B bf16 row-major (M,K)/(N,K). 128x128 tile, BK=64, 4 waves,
// single-buffered LDS [128][64] linear dest via global_load_lds dwordx4.
// Swizzle pair: global source col pre-XOR'd with row&7 (16B chunks); ds_read
// col XOR'd identically -> 0 bank conflicts (verified R3-R6).
// 32 KB LDS -> 5 blocks/CU: inter-block overlap hides barrier drains (m114).
// EPI 0: out_bf16 = relu(acc + bias[n])
// EPI 3: scores[m] += sum_n tanh(acc + bias[n] + atth[m/49][n]) * alphaW[n]
template<int EPI>
__global__ __launch_bounds__(256)
void k_fast(const unsigned short* __restrict__ A,
            const unsigned short* __restrict__ B,
            const float* __restrict__ bias, void* __restrict__ out,
            const float* __restrict__ atth, const float* __restrict__ alphaW,
            int M, int N, int K) {
    __shared__ __align__(16) unsigned short As[128 * 64];
    __shared__ __align__(16) unsigned short Bs[128 * 64];

    const int tid  = threadIdx.x;
    const int lane = tid & 63;
    const int wave = tid >> 6;

    // XCD-bijective mapping: nwg = nmt*nnt, divisible by 8. Each XCD owns a
    // contiguous band of n-tiles -> its B panels stay L2-resident.
    const int nmt = M >> 7;                       // 98
    const int cpx = (nmt * (N >> 7)) >> 3;        // 196 blocks per XCD
    const int wg  = (blockIdx.x & 7) * cpx + (blockIdx.x >> 3);
    const int m0 = (wg % nmt) * 128;
    const int n0 = (wg / nmt) * 128;

    const int wm = (wave >> 1) * 64;
    const int wn = (wave & 1) * 64;

    // staging: chunk = wave*4+i covers LDS rows chunk*8..+8 (linear dest);
    // global col pre-swizzled by row&7 in 16B chunks.
    const int srow = lane >> 3;                   // row within 8-row chunk
    const int scol = ((lane & 7) ^ srow) << 3;    // pre-swizzled col (elems)

    // read-side swizzled col offsets (elems), keyed on row&7 == lane&7
    const int rfrag = lane & 15;
    const int ck0 = (((lane >> 4) << 3)) ^ ((lane & 7) << 3);
    const int ck1 = (32 + ((lane >> 4) << 3)) ^ ((lane & 7) << 3);

    f32x4 acc[4][4];
#pragma unroll
    for (int i = 0; i < 4; ++i)
#pragma unroll
        for (int j = 0; j < 4; ++j)
#pragma unroll
            for (int r = 0; r < 4; ++r) acc[i][j][r] = 0.f;

    for (int kt = 0; kt < K; kt += 64) {
        __syncthreads();
#pragma unroll
        for (int i = 0; i < 4; ++i) {
            const int chunk = wave * 4 + i;
            const int r = chunk * 8 + srow;
            __builtin_amdgcn_global_load_lds(
                (const __attribute__((address_space(1))) void*)(A + (size_t)(m0 + r) * K + kt + scol),
                (__attribute__((address_space(3))) void*)(&As[chunk * 512]), 16, 0, 0);
            __builtin_amdgcn_global_load_lds(
                (const __attribute__((address_space(1))) void*)(B + (size_t)(n0 + r) * K + kt + scol),
                (__attribute__((address_space(3))) void*)(&Bs[chunk * 512]), 16, 0, 0);
        }
        __syncthreads();   // compiler drains vmcnt before barrier

#pragma unroll
        for (int ks = 0; ks < 2; ++ks) {
            const int cka = ks ? ck1 : ck0;
            bf16x8 af[4], bfr[4];
#pragma unroll
            for (int i = 0; i < 4; ++i)
                af[i] = *(const bf16x8*)&As[(wm + i * 16 + rfrag) * 64 + cka];
#pragma unroll
            for (int j = 0; j < 4; ++j)
                bfr[j] = *(const bf16x8*)&Bs[(wn + j * 16 + rfrag) * 64 + cka];
#pragma unroll
            for (int i = 0; i < 4; ++i)
#pragma unroll
                for (int j = 0; j < 4; ++j)
                    acc[i][j] = __builtin_amdgcn_mfma_f32_16x16x32_bf16(
                        af[i], bfr[j], acc[i][j], 0, 0, 0);
        }
    }

    // epilogue — D layout (verified): col = lane&15, row = (lane>>4)*4 + r
#pragma unroll
    for (int i = 0; i < 4; ++i) {
#pragma unroll
        for (int r = 0; r < 4; ++r) {
            const int gm = m0 + wm + i * 16 + ((lane >> 4) << 2) + r;
            if constexpr (EPI == 3) {
                float partial = 0.f;
                const int b = gm / Sn;
#pragma unroll
                for (int j = 0; j < 4; ++j) {
                    const int gn = n0 + wn + j * 16 + rfrag;
                    float v = acc[i][j][r] + bias[gn] + atth[(size_t)b * N + gn];
                    partial += tanhf(v) * alphaW[gn];
                }
#pragma unroll
                for (int off = 1; off < 16; off <<= 1)
                    partial += __shfl_xor(partial, off);
                if (rfrag == 0) atomicAdd(&((float*)out)[gm], partial);
            } else {
#pragma unroll
                for (int j = 0; j < 4; ++j) {
                    const int gn = n0 + wn + j * 16 + rfrag;
                    float v = acc[i][j][r] + bias[gn];
                    ((unsigned short*)out)[(size_t)gm * N + gn] = f2bf(v > 0.f ? v : 0.f);
                }
            }
        }
    }
}

// ==================== fused pre-GEMM: sums (dual) + atth ====================
// grid (96, 2): blocks x<80 -> sums = xt@i2h^T + h@h2h^T + biases (N=10240)
//               blocks x>=80 -> atth = h@h2att_W^T + h2att_b     (N=2048)
__global__ __launch_bounds__(256)
void k_gemm_pre(const unsigned short* __restrict__ xtb,
                const unsigned short* __restrict__ hb,
                const float* __restrict__ i2h_W, const float* __restrict__ h2h_W,
                const float* __restrict__ h2att_W,
                const float* __restrict__ i2h_b, const float* __restrict__ h2h_b,
                const float* __restrict__ h2att_b,
                float* __restrict__ sums, float* __restrict__ atth) {
    __shared__ __align__(16) unsigned short As[128 * LDP];
    __shared__ __align__(16) unsigned short Bs[128 * LDP];

    const int K = Hn;
    const bool isPre = blockIdx.x < 80;
    const int n0 = (isPre ? blockIdx.x : (blockIdx.x - 80)) * 128;
    const int Nld = isPre ? 5 * Hn : Hn;
    float* outp = isPre ? sums : atth;

    const int tid = threadIdx.x;
    const int m0 = blockIdx.y * 128;
    const int lane = tid & 63;
    const int wave = tid >> 6;
    const int wm = (wave >> 1) * 64;
    const int wn = (wave & 1) * 64;

    f32x4 acc[4][4];
#pragma unroll
    for (int i = 0; i < 4; ++i)
#pragma unroll
        for (int j = 0; j < 4; ++j)
#pragma unroll
            for (int r = 0; r < 4; ++r) acc[i][j][r] = 0.f;

    const int npass = isPre ? 2 : 1;
    for (int pass = 0; pass < npass; ++pass) {
        const unsigned short* Ap = pass ? hb : (isPre ? xtb : hb);
        const float* Bp = pass ? h2h_W : (isPre ? i2h_W : h2att_W);
        for (int kt = 0; kt < K; kt += 64) {
            __syncthreads();
            {   // stage A (bf16)
                const int r = tid >> 3, c = (tid & 7) << 3;
                const unsigned short* src = Ap + (size_t)(m0 + r) * K + kt + c;
#pragma unroll
                for (int i = 0; i < 4; ++i) {
                    int4 v = *(const int4*)(src + (size_t)i * 32 * K);
                    *(int4*)&As[(r + i * 32) * LDP + c] = v;
                }
            }
            {   // stage B from f32, converting
                const int r = tid >> 4, c = (tid & 15) << 2;
                const float* src = Bp + (size_t)(n0 + r) * K + kt + c;
#pragma unroll
                for (int i = 0; i < 8; ++i) {
                    float4 v = *(const float4*)(src + (size_t)i * 16 * K);
                    union { unsigned short us[4]; uint2 u2; } t;
                    t.us[0] = f2bf(v.x); t.us[1] = f2bf(v.y);
                    t.us[2] = f2bf(v.z); t.us[3] = f2bf(v.w);
                    *(uint2*)&Bs[(r + i * 16) * LDP + c] = t.u2;
                }
            }
            __syncthreads();
#pragma unroll
            for (int ks = 0; ks < 64; ks += 32) {
                const int col = ks + ((lane >> 4) << 3);
                const int ra = wm + (lane & 15);
                const int rb = wn + (lane & 15);
                bf16x8 af[4], bfr[4];
#pragma unroll
                for (int i = 0; i < 4; ++i)
                    af[i] = *(const bf16x8*)&As[(ra + i * 16) * LDP + col];
#pragma unroll
                for (int j = 0; j < 4; ++j)
                    bfr[j] = *(const bf16x8*)&Bs[(rb + j * 16) * LDP + col];
#pragma unroll
                for (int i = 0; i < 4; ++i)
#pragma unroll
                    for (int j = 0; j < 4; ++j)
                        acc[i][j] = __builtin_amdgcn_mfma_f32_16x16x32_bf16(
                            af[i], bfr[j], acc[i][j], 0, 0, 0);
            }
        }
    }

#pragma unroll
    for (int i = 0; i < 4; ++i) {
#pragma unroll
        for (int r = 0; r < 4; ++r) {
            const int gm = m0 + wm + i * 16 + ((lane >> 4) << 2) + r;
#pragma unroll
            for (int j = 0; j < 4; ++j) {
                const int gn = n0 + wn + j * 16 + (lane & 15);
                float v = acc[i][j][r] +
                          (isPre ? (i2h_b[gn] + h2h_b[gn]) : h2att_b[gn]);
                outp[(size_t)gm * Nld + gn] = v;
            }
        }
    }
}

// ==================== small GEMM (register-staged, f32 B converted) =========
__global__ __launch_bounds__(256)
void k_gemm_s(const unsigned short* __restrict__ A, const float* __restrict__ B,
              const float* __restrict__ bias,
              float* __restrict__ out, int M, int N, int K) {
    __shared__ __align__(16) unsigned short As[128 * LDP];
    __shared__ __align__(16) unsigned short Bs[128 * LDP];

    const int tid = threadIdx.x;
    const int m0 = blockIdx.y * 128;
    const int n0 = blockIdx.x * 128;
    const int lane = tid & 63;
    const int wave = tid >> 6;
    const int wm = (wave >> 1) * 64;
    const int wn = (wave & 1) * 64;

    f32x4 acc[4][4];
#pragma unroll
    for (int i = 0; i < 4; ++i)
#pragma unroll
        for (int j = 0; j < 4; ++j)
#pragma unroll
            for (int r = 0; r < 4; ++r) acc[i][j][r] = 0.f;

    for (int kt = 0; kt < K; kt += 64) {
        __syncthreads();
        {   // stage A (bf16)
            const int r = tid >> 3, c = (tid & 7) << 3;
            const unsigned short* src = A + (size_t)(m0 + r) * K + kt + c;
#pragma unroll
            for (int i = 0; i < 4; ++i) {
                int4 v = *(const int4*)(src + (size_t)i * 32 * K);
                *(int4*)&As[(r + i * 32) * LDP + c] = v;
            }
        }
        {   // stage B from f32, converting
            const int r = tid >> 4, c = (tid & 15) << 2;
            const float* src = B + (size_t)(n0 + r) * K + kt + c;
#pragma unroll
            for (int i = 0; i < 8; ++i) {
                float4 v = *(const float4*)(src + (size_t)i * 16 * K);
                union { unsigned short us[4]; uint2 u2; } t;
                t.us[0] = f2bf(v.x); t.us[1] = f2bf(v.y);
                t.us[2] = f2bf(v.z); t.us[3] = f2bf(v.w);
                *(uint2*)&Bs[(r + i * 16) * LDP + c] = t.u2;
            }
        }
        __syncthreads();
#pragma unroll
        for (int ks = 0; ks < 64; ks += 32) {
            const int col = ks + ((lane >> 4) << 3);
            const int ra = wm + (lane & 15);
            const int rb = wn + (lane & 15);
            bf16x8 af[4], bfr[4];
#pragma unroll
            for (int i = 0; i < 4; ++i)
                af[i] = *(const bf16x8*)&As[(ra + i * 16) * LDP + col];
#pragma unroll
            for (int j = 0; j < 4; ++j)
                bfr[j] = *(const bf16x8*)&Bs[(rb + j * 16) * LDP + col];
#pragma unroll
            for (int i = 0; i < 4; ++i)
#pragma unroll
                for (int j = 0; j < 4; ++j)
                    acc[i][j] = __builtin_amdgcn_mfma_f32_16x16x32_bf16(
                        af[i], bfr[j], acc[i][j], 0, 0, 0);
        }
    }

#pragma unroll
    for (int i = 0; i < 4; ++i) {
#pragma unroll
        for (int r = 0; r < 4; ++r) {
            const int gm = m0 + wm + i * 16 + ((lane >> 4) << 2) + r;
#pragma unroll
            for (int j = 0; j < 4; ++j) {
                const int gn = n0 + wn + j * 16 + (lane & 15);
                out[(size_t)gm * N + gn] = acc[i][j][r] + bias[gn];
            }
        }
    }
}

// ------ att_res[b,h] = sum_s softmax(scores[b])_s * att_feats[b,s,h] --------
__global__ void k_attres_sm(const float* __restrict__ scores,
                            const unsigned short* __restrict__ attf,
                            unsigned short* __restrict__ attres) {
    int b = blockIdx.y;
    int h = blockIdx.x * blockDim.x + threadIdx.x;
    const float* sc = scores + b * Sn;
    float m = -1e30f;
#pragma unroll 7
    for (int s = 0; s < Sn; ++s) m = fmaxf(m, sc[s]);
    float sum = 0.f;
#pragma unroll 7
    for (int s = 0; s < Sn; ++s) sum += __expf(sc[s] - m);
    const float inv = 1.f / sum;
    const unsigned short* p = attf + (size_t)b * Sn * Hn + h;
    float acc = 0.f;
#pragma unroll 7
    for (int s = 0; s < Sn; ++s)
        acc += __expf(sc[s] - m) * bf2f(p[(size_t)s * Hn]);
    attres[(size_t)b * Hn + h] = f2bf(acc * inv);
}

// -------------------- LSTM tail ---------------------------------------------
__global__ void k_final(const float* __restrict__ sums, const float* __restrict__ a2c,
                        const float* __restrict__ state, const int* __restrict__ timep,
                        float* __restrict__ out) {
    int idx = blockIdx.x * blockDim.x + threadIdx.x;  // over B*H
    int b = idx >> 11, h = idx & (Hn - 1);
    const float* srow = sums + (size_t)b * 5 * Hn;
    float ig = 1.f / (1.f + __expf(-srow[h]));
    float fg = 1.f / (1.f + __expf(-srow[Hn + h]));
    float og = 1.f / (1.f + __expf(-srow[2 * Hn + h]));
    float t1 = srow[3 * Hn + h] + a2c[(size_t)b * 2 * Hn + h];
    float t2 = srow[4 * Hn + h] + a2c[(size_t)b * 2 * Hn + Hn + h];
    float intr = fmaxf(t1, t2);
    float cprev = (timep[0] == 0) ? 0.f : state[(size_t)Bn * Hn + idx];  // state[1,0,b,:]
    float c = fg * cprev + ig * intr;
    float hh = og * tanhf(c);
    const int BH = Bn * Hn;
    out[idx] = hh;            // output (B,1,H)
    out[BH + idx] = hh;       // next_h (1,B,H)
    out[2 * BH + idx] = c;    // next_c (1,B,H)
}

// ---------------------------------------------------------------------------
extern "C" void kernel_launch(void* const* d_in, const int* in_sizes, int n_in,
                              void* d_out, int out_size, void* d_ws, size_t ws_size,
                              hipStream_t stream) {
    const float* V        = (const float*)d_in[0];
    const float* state    = (const float*)d_in[2];
    const int*   captions = (const int*)d_in[3];
    const int*   timep    = (const int*)d_in[4];
    const float* att_W    = (const float*)d_in[7];
    const float* att_b    = (const float*)d_in[8];
    const float* emb      = (const float*)d_in[9];
    const float* ctx_W    = (const float*)d_in[10];
    const float* ctx_b    = (const float*)d_in[11];
    const float* a2c_W    = (const float*)d_in[12];
    const float* a2c_b    = (const float*)d_in[13];
    const float* i2h_W    = (const float*)d_in[14];
    const float* i2h_b    = (const float*)d_in[15];
    const float* h2h_W    = (const float*)d_in[16];
    const float* h2h_b    = (const float*)d_in[17];
    const float* h2att_W  = (const float*)d_in[18];
    const float* h2att_b  = (const float*)d_in[19];
    const float* alpha_W  = (const float*)d_in[20];

    // workspace layout (bf16 elems first, then f32)
    unsigned short* Vb      = (unsigned short*)d_ws;        // 25,690,112
    unsigned short* attWb   = Vb + (size_t)Mrows * Hn;      //  4,194,304
    unsigned short* ctxWb   = attWb + (size_t)Hn * Hn;      //  4,194,304
    unsigned short* attfb   = ctxWb + (size_t)Hn * Hn;      // 25,690,112
    unsigned short* xtb     = attfb + (size_t)Mrows * Hn;   //    524,288
    unsigned short* hb      = xtb + Bn * Hn;                //    524,288
    unsigned short* attresb = hb + Bn * Hn;                 //    524,288
    float* atth    = (float*)(attresb + Bn * Hn);           //    524,288 f32
    float* scores  = atth + Bn * Hn;                        //     12,544
    float* weight  = scores + Mrows;                        //     12,544 (unused)
    float* sums    = weight + Mrows;                        //  2,621,440
    float* a2c_out = sums + (size_t)Bn * 5 * Hn;            //  1,048,576

    hipMemsetAsync(scores, 0, Mrows * sizeof(float), stream);

    const int nc0 = Mrows * Hn / 8, nc1 = Hn * Hn / 8, nc2 = Hn * Hn / 8;
    k_convert3<<<(nc0 + nc1 + nc2 + 255) / 256, 256, 0, stream>>>(
        V, Vb, nc0, att_W, attWb, nc1, ctx_W, ctxWb, nc2);
    k_gather<<<Bn, 256, 0, stream>>>(emb, state, captions, timep, xtb, hb);

    const int nwg = (Mrows / 128) * (Hn / 128);   // 98*16 = 1568, %8 == 0

    // att_feats = relu(V @ att_W^T + att_b) -> bf16   [128^2 fast]
    k_fast<0><<<nwg, 256, 0, stream>>>(
        Vb, attWb, att_b, attfb, nullptr, nullptr, Mrows, Hn, Hn);
    // fused: sums = xt@i2h^T + h@h2h^T + biases ; atth = h@h2att^T + h2att_b
    k_gemm_pre<<<dim3(96, 2), 256, 0, stream>>>(
        xtb, hb, i2h_W, h2h_W, h2att_W, i2h_b, h2h_b, h2att_b, sums, atth);
    // scores[m] = sum_n tanh(att_feats@ctx_W^T + ctx_b + att_h) * alpha_W
    k_fast<3><<<nwg, 256, 0, stream>>>(
        attfb, ctxWb, ctx_b, scores, atth, alpha_W, Mrows, Hn, Hn);
    // att_res with fused row-softmax
    k_attres_sm<<<dim3(Hn / 256, Bn), 256, 0, stream>>>(scores, attfb, attresb);
    // a2c_out = att_res @ a2c_W^T + a2c_b  (f32 out)
    k_gemm_s<<<dim3(2 * Hn / 128, Bn / 128), 256, 0, stream>>>(
        attresb, a2c_W, a2c_b, a2c_out, Bn, 2 * Hn, Hn);

    k_final<<<Bn * Hn / 256, 256, 0, stream>>>(sums, a2c_out, state, timep, (float*)d_out);
}

// Round 9
// 518.701 us; speedup vs baseline: 1.1617x; 1.1617x over previous
//
#include <hip/hip_runtime.h>

// ---------------------------------------------------------------------------
// Att2in2Core: B=256, S=49, H=2048, V_SZ=10000
// fc_* / v_g are dead code in the reference; alpha_b is softmax-invariant.
// R8 finding: ALL GEMM variants are fetch-bound (dur == hbm_bytes/BW in every
// case; FETCH ~= 4-8x the 51MB A panel -> cross-XCD re-fetch from n-column
// XCD ownership). R9: m-band XCD ownership, n-fastest inner order: A read
// once per m-tile (L2-held across its 8 n-tiles), B shared via L3.
// gemm8 v3 schedule (R6: 176us, 0 conflicts, 0 spill) otherwise unchanged.
// ---------------------------------------------------------------------------

typedef __bf16 bf16x8 __attribute__((ext_vector_type(8)));
typedef float  f32x4  __attribute__((ext_vector_type(4)));

static constexpr int Bn = 256;
static constexpr int Sn = 49;
static constexpr int Hn = 2048;
static constexpr int Mrows = Bn * Sn;      // 12544
static constexpr int LDP = 72;             // padded LDS stride (small-GEMM path)

__device__ __forceinline__ unsigned short f2bf(float f) {
    unsigned u = __builtin_bit_cast(unsigned, f);
    u += 0x7FFFu + ((u >> 16) & 1u);       // round-to-nearest-even
    return (unsigned short)(u >> 16);
}
__device__ __forceinline__ float bf2f(unsigned short h) {
    return __builtin_bit_cast(float, ((unsigned)h) << 16);
}

// -------------------- fused f32 -> bf16 convert of V, att_W, ctx_W ---------
__global__ void k_convert3(const float* __restrict__ s0, unsigned short* __restrict__ d0, int n0,
                           const float* __restrict__ s1, unsigned short* __restrict__ d1, int n1,
                           const float* __restrict__ s2, unsigned short* __restrict__ d2, int n2) {
    int i = blockIdx.x * blockDim.x + threadIdx.x;   // unit = 8 elems
    const float* src; unsigned short* dst;
    if (i < n0)            { src = s0; dst = d0; }
    else if (i < n0 + n1)  { src = s1; dst = d1; i -= n0; }
    else if (i < n0 + n1 + n2) { src = s2; dst = d2; i -= n0 + n1; }
    else return;
    const float4* p = (const float4*)src + (size_t)i * 2;
    float4 a = p[0], b = p[1];
    union { unsigned short us[8]; int4 v; } o;
    o.us[0] = f2bf(a.x); o.us[1] = f2bf(a.y); o.us[2] = f2bf(a.z); o.us[3] = f2bf(a.w);
    o.us[4] = f2bf(b.x); o.us[5] = f2bf(b.y); o.us[6] = f2bf(b.z); o.us[7] = f2bf(b.w);
    ((int4*)dst)[i] = o.v;
}

// -------------------- gather xt = relu(emb[captions[:,t]]), h_prev ----------
__global__ void k_gather(const float* __restrict__ emb,
                         const float* __restrict__ state,
                         const int* __restrict__ captions,
                         const int* __restrict__ timep,
                         unsigned short* __restrict__ xt_b,
                         unsigned short* __restrict__ h_b) {
    int b = blockIdx.x;
    int tm = timep[0];
    int it = captions[b * 16 + tm];
    const float* erow = emb + (size_t)it * Hn;
    for (int h = threadIdx.x; h < Hn; h += blockDim.x) {
        float x = erow[h];
        xt_b[(size_t)b * Hn + h] = f2bf(x > 0.f ? x : 0.f);
        float hv = (tm == 0) ? 0.f : state[(size_t)b * Hn + h];  // state[0,0,b,:]
        h_b[(size_t)b * Hn + h] = f2bf(hv);
    }
}

// ==================== 256^2 8-phase MFMA GEMM (v3 + m-band XCD map) =========
// C = A @ B^T, bf16 row-major. BM=BN=256, BK=64, 8 waves (2Mx4N), per-wave
// output 128x64, acc[8][4] f32x4 (128 AGPR). LDS 128KiB [dbuf][A/B][half],
// XOR-swizzled on read + pre-swizzled global src, linear gload_lds dest.
// N must be 2048 (8 n-tiles). XCD x owns tiles t in [x*nm, x*nm+nm); inner
// order n-fastest so each A m-tile (1MB) stays L2-resident for its 8 n-tiles.
template<int EPI>
__global__ __launch_bounds__(512, 1)
void k_gemm8(const unsigned short* __restrict__ A,
             const unsigned short* __restrict__ B,
             const float* __restrict__ bias, void* __restrict__ out,
             const float* __restrict__ atth, const float* __restrict__ alphaW,
             int M, int N, int K) {
    __shared__ __align__(16) unsigned short lds[2][2][2][128 * 64];

    const int tid  = threadIdx.x;
    const int lane = tid & 63;
    const int wave = tid >> 6;
    const int wm = wave >> 2;        // 0..1  (M half)
    const int wn = wave & 3;         // 0..3  (N quarter)
    const int wh = wn >> 1;          // B half this wave reads

    // m-band XCD mapping (R9): t = xcd*nm + local; m = t/8 (m-band per XCD),
    // n = t%8 (n-fastest -> A-tile L2 reuse). Requires N == 2048.
    const int nm = M >> 8;                              // m-tiles (49)
    const int t  = (blockIdx.x & 7) * nm + (blockIdx.x >> 3);
    const int m_tile = t >> 3;
    const int n_tile = t & 7;
    const size_t am0 = (size_t)m_tile * 256;
    const size_t bn0 = (size_t)n_tile * 256;

    const int srow = lane >> 3;                      // 0..7
    const int scol = (((lane & 7) ^ srow)) * 8;      // pre-swizzled col offset

#define STG(SLOT, G, RBASE, KT)                                              \
    {                                                                        \
        _Pragma("unroll")                                                    \
        for (int j_ = 0; j_ < 2; ++j_) {                                     \
            const int rr_ = (wave * 2 + j_) * 8 + srow;                      \
            const unsigned short* src_ =                                     \
                (G) + ((RBASE) + rr_) * (size_t)K + (KT) * 64 + scol;        \
            __builtin_amdgcn_global_load_lds(                                \
                (const __attribute__((address_space(1))) void*)src_,         \
                (__attribute__((address_space(3))) void*)((SLOT) + (wave * 2 + j_) * 512), \
                16, 0, 0);                                                   \
        }                                                                    \
    }

    unsigned short* SA0_0 = &lds[0][0][0][0];
    unsigned short* SA0_1 = &lds[0][0][1][0];
    unsigned short* SB0_0 = &lds[0][1][0][0];
    unsigned short* SB0_1 = &lds[0][1][1][0];
    unsigned short* SA1_0 = &lds[1][0][0][0];
    unsigned short* SA1_1 = &lds[1][0][1][0];
    unsigned short* SB1_0 = &lds[1][1][0][0];
    unsigned short* SB1_1 = &lds[1][1][1][0];

    const unsigned short* As0r = &lds[0][0][wm][0];
    const unsigned short* As1r = &lds[1][0][wm][0];
    const unsigned short* Bs0r = &lds[0][1][wh][0];
    const unsigned short* Bs1r = &lds[1][1][wh][0];

    const int rfrag = lane & 15;
    const int wnl = (wn & 1) * 64;
    const int ck0 = (((lane >> 4) * 8)) ^ ((lane & 7) * 8);
    const int ck1 = (32 + ((lane >> 4) * 8)) ^ ((lane & 7) * 8);

    f32x4 acc[8][4];
#pragma unroll
    for (int m = 0; m < 8; ++m)
#pragma unroll
        for (int n = 0; n < 4; ++n)
#pragma unroll
            for (int r = 0; r < 4; ++r) acc[m][n][r] = 0.f;

    bf16x8 bfr[4][2], pf0[2][2], pf1[2][2];

#define RDA(ASR, TP, PF)                                                     \
    _Pragma("unroll")                                                        \
    for (int mm = 0; mm < 2; ++mm) {                                         \
        PF[mm][0] = *(const bf16x8*)&(ASR)[((2 * (TP) + mm) * 16 + rfrag) * 64 + ck0]; \
        PF[mm][1] = *(const bf16x8*)&(ASR)[((2 * (TP) + mm) * 16 + rfrag) * 64 + ck1]; \
    }
#define RDB(BSR)                                                             \
    _Pragma("unroll")                                                        \
    for (int n = 0; n < 4; ++n) {                                            \
        bfr[n][0] = *(const bf16x8*)&(BSR)[(wnl + n * 16 + rfrag) * 64 + ck0]; \
        bfr[n][1] = *(const bf16x8*)&(BSR)[(wnl + n * 16 + rfrag) * 64 + ck1]; \
    }
#define MM(PF, TP)                                                           \
    __builtin_amdgcn_s_setprio(1);                                           \
    _Pragma("unroll")                                                        \
    for (int mm = 0; mm < 2; ++mm)                                           \
        _Pragma("unroll")                                                    \
        for (int n = 0; n < 4; ++n)                                          \
            _Pragma("unroll")                                                \
            for (int s = 0; s < 2; ++s)                                      \
                acc[2 * (TP) + mm][n] = __builtin_amdgcn_mfma_f32_16x16x32_bf16( \
                    PF[mm][s], bfr[n][s], acc[2 * (TP) + mm][n], 0, 0, 0);   \
    __builtin_amdgcn_s_setprio(0);

#define FENCE  __builtin_amdgcn_sched_barrier(0)
#define LGKM0  asm volatile("s_waitcnt lgkmcnt(0)" ::: "memory")
#define VM4    asm volatile("s_waitcnt vmcnt(4)" ::: "memory")
#define BAR    __builtin_amdgcn_s_barrier()

    // ---- prologue: stage P(kt0) -> dbuf0, wait; load regs; stage Q(kt1) ----
    STG(SB0_0, B, bn0 + 0,   0);
    STG(SB0_1, B, bn0 + 128, 0);
    STG(SA0_0, A, am0 + 0,   0);
    STG(SA0_1, A, am0 + 128, 0);
    asm volatile("s_waitcnt vmcnt(0)" ::: "memory");
    BAR;
    RDB(Bs0r);
    RDA(As0r, 0, pf0);
    STG(SB1_0, B, bn0 + 0,   1);
    STG(SB1_1, B, bn0 + 128, 1);
    STG(SA1_0, A, am0 + 0,   1);
    STG(SA1_1, A, am0 + 128, 1);
    LGKM0;           // all waves' reg reads done before ph0's STG can clobber
    BAR;

    const int KT_MAX = K / 64 - 1;
    for (int it = 0; it < K / 128; ++it) {
        const int ktP2 = (2 * it + 2 < KT_MAX) ? 2 * it + 2 : KT_MAX;
        const int ktQ3 = (2 * it + 3 < KT_MAX) ? 2 * it + 3 : KT_MAX;
        // ph0
        RDA(As0r, 1, pf1); FENCE;
        MM(pf0, 0);
        LGKM0; FENCE;
        STG(SB0_0, B, bn0 + 0, ktP2);
        BAR;
        // ph1
        RDA(As0r, 2, pf0); FENCE;
        MM(pf1, 1);
        LGKM0; FENCE;
        STG(SB0_1, B, bn0 + 128, ktP2);
        BAR;
        // ph2
        RDA(As0r, 3, pf1); FENCE;
        MM(pf0, 2);
        LGKM0; FENCE;
        VM4;             // completes Q.B + Q.A before ph3 reads dbuf1
        BAR;
        // ph3 — last use of bfr(dbuf0); reload with dbuf1 AFTER the MM
        RDA(As1r, 0, pf0); FENCE;
        MM(pf1, 3);
        RDB(Bs1r); FENCE;
        LGKM0; FENCE;
        STG(SA0_0, A, am0 + 0, ktP2);
        BAR;
        // ph4
        RDA(As1r, 1, pf1); FENCE;
        MM(pf0, 0);
        LGKM0; FENCE;
        STG(SA0_1, A, am0 + 128, ktP2);
        STG(SB1_0, B, bn0 + 0, ktQ3);
        BAR;
        // ph5
        RDA(As1r, 2, pf0); FENCE;
        MM(pf1, 1);
        LGKM0; FENCE;
        STG(SB1_1, B, bn0 + 128, ktQ3);
        BAR;
        // ph6
        RDA(As1r, 3, pf1); FENCE;
        MM(pf0, 2);
        LGKM0; FENCE;
        VM4;             // completes P2.B + P2.A before ph7 reads dbuf0
        BAR;
        // ph7 — last use of bfr(dbuf1); reload with dbuf0 (ktP2) AFTER the MM
        RDA(As0r, 0, pf0); FENCE;
        MM(pf1, 3);
        RDB(Bs0r); FENCE;
        LGKM0; FENCE;
        STG(SA1_0, A, am0 + 0, ktQ3);
        STG(SA1_1, A, am0 + 128, ktQ3);
        BAR;
    }
#undef STG
#undef RDA
#undef RDB
#undef MM

    asm volatile("s_waitcnt vmcnt(0)" ::: "memory");

    // epilogue — D layout (verified): col = lane&15, row = (lane>>4)*4 + r
    const int rq = (lane >> 4) << 2;
#pragma unroll
    for (int m = 0; m < 8; ++m) {
#pragma unroll
        for (int r = 0; r < 4; ++r) {
            const size_t gm = am0 + (size_t)wm * 128 + m * 16 + rq + r;
            if constexpr (EPI == 3) {
                float partial = 0.f;
                const int b = (int)(gm / Sn);
#pragma unroll
                for (int n = 0; n < 4; ++n) {
                    const int gn = (int)bn0 + wn * 64 + n * 16 + rfrag;
                    float v = acc[m][n][r] + bias[gn] + atth[(size_t)b * N + gn];
                    partial += tanhf(v) * alphaW[gn];
                }
#pragma unroll
                for (int off = 1; off < 16; off <<= 1)
                    partial += __shfl_xor(partial, off);
                if (rfrag == 0) atomicAdd(&((float*)out)[gm], partial);
            } else {
#pragma unroll
                for (int n = 0; n < 4; ++n) {
                    const int gn = (int)bn0 + wn * 64 + n * 16 + rfrag;
                    float v = acc[m][n][r] + bias[gn];
                    ((unsigned short*)out)[gm * N + gn] = f2bf(v > 0.f ? v : 0.f);
                }
            }
        }
    }
}

// ==================== fused pre-GEMM: sums (dual) + atth ====================
// grid (96, 2): blocks x<80 -> sums = xt@i2h^T + h@h2h^T + biases (N=10240)
//               blocks x>=80 -> atth = h@h2att_W^T + h2att_b     (N=2048)
__global__ __launch_bounds__(256)
void k_gemm_pre(const unsigned short* __restrict__ xtb,
                const unsigned short* __restrict__ hb,
                const float* __restrict__ i2h_W, const float* __restrict__ h2h_W,
                const float* __restrict__ h2att_W,
                const float* __restrict__ i2h_b, const float* __restrict__ h2h_b,
                const float* __restrict__ h2att_b,
                float* __restrict__ sums, float* __restrict__ atth) {
    __shared__ __align__(16) unsigned short As[128 * LDP];
    __shared__ __align__(16) unsigned short Bs[128 * LDP];

    const int K = Hn;
    const bool isPre = blockIdx.x < 80;
    const int n0 = (isPre ? blockIdx.x : (blockIdx.x - 80)) * 128;
    const int Nld = isPre ? 5 * Hn : Hn;
    float* outp = isPre ? sums : atth;

    const int tid = threadIdx.x;
    const int m0 = blockIdx.y * 128;
    const int lane = tid & 63;
    const int wave = tid >> 6;
    const int wm = (wave >> 1) * 64;
    const int wn = (wave & 1) * 64;

    f32x4 acc[4][4];
#pragma unroll
    for (int i = 0; i < 4; ++i)
#pragma unroll
        for (int j = 0; j < 4; ++j)
#pragma unroll
            for (int r = 0; r < 4; ++r) acc[i][j][r] = 0.f;

    const int npass = isPre ? 2 : 1;
    for (int pass = 0; pass < npass; ++pass) {
        const unsigned short* Ap = pass ? hb : (isPre ? xtb : hb);
        const float* Bp = pass ? h2h_W : (isPre ? i2h_W : h2att_W);
        for (int kt = 0; kt < K; kt += 64) {
            __syncthreads();
            {   // stage A (bf16)
                const int r = tid >> 3, c = (tid & 7) << 3;
                const unsigned short* src = Ap + (size_t)(m0 + r) * K + kt + c;
#pragma unroll
                for (int i = 0; i < 4; ++i) {
                    int4 v = *(const int4*)(src + (size_t)i * 32 * K);
                    *(int4*)&As[(r + i * 32) * LDP + c] = v;
                }
            }
            {   // stage B from f32, converting
                const int r = tid >> 4, c = (tid & 15) << 2;
                const float* src = Bp + (size_t)(n0 + r) * K + kt + c;
#pragma unroll
                for (int i = 0; i < 8; ++i) {
                    float4 v = *(const float4*)(src + (size_t)i * 16 * K);
                    union { unsigned short us[4]; uint2 u2; } t;
                    t.us[0] = f2bf(v.x); t.us[1] = f2bf(v.y);
                    t.us[2] = f2bf(v.z); t.us[3] = f2bf(v.w);
                    *(uint2*)&Bs[(r + i * 16) * LDP + c] = t.u2;
                }
            }
            __syncthreads();
#pragma unroll
            for (int ks = 0; ks < 64; ks += 32) {
                const int col = ks + ((lane >> 4) << 3);
                const int ra = wm + (lane & 15);
                const int rb = wn + (lane & 15);
                bf16x8 af[4], bfr[4];
#pragma unroll
                for (int i = 0; i < 4; ++i)
                    af[i] = *(const bf16x8*)&As[(ra + i * 16) * LDP + col];
#pragma unroll
                for (int j = 0; j < 4; ++j)
                    bfr[j] = *(const bf16x8*)&Bs[(rb + j * 16) * LDP + col];
#pragma unroll
                for (int i = 0; i < 4; ++i)
#pragma unroll
                    for (int j = 0; j < 4; ++j)
                        acc[i][j] = __builtin_amdgcn_mfma_f32_16x16x32_bf16(
                            af[i], bfr[j], acc[i][j], 0, 0, 0);
            }
        }
    }

#pragma unroll
    for (int i = 0; i < 4; ++i) {
#pragma unroll
        for (int r = 0; r < 4; ++r) {
            const int gm = m0 + wm + i * 16 + ((lane >> 4) << 2) + r;
#pragma unroll
            for (int j = 0; j < 4; ++j) {
                const int gn = n0 + wn + j * 16 + (lane & 15);
                float v = acc[i][j][r] +
                          (isPre ? (i2h_b[gn] + h2h_b[gn]) : h2att_b[gn]);
                outp[(size_t)gm * Nld + gn] = v;
            }
        }
    }
}

// ==================== small GEMM (register-staged, f32 B converted) =========
__global__ __launch_bounds__(256)
void k_gemm_s(const unsigned short* __restrict__ A, const float* __restrict__ B,
              const float* __restrict__ bias,
              float* __restrict__ out, int M, int N, int K) {
    __shared__ __align__(16) unsigned short As[128 * LDP];
    __shared__ __align__(16) unsigned short Bs[128 * LDP];

    const int tid = threadIdx.x;
    const int m0 = blockIdx.y * 128;
    const int n0 = blockIdx.x * 128;
    const int lane = tid & 63;
    const int wave = tid >> 6;
    const int wm = (wave >> 1) * 64;
    const int wn = (wave & 1) * 64;

    f32x4 acc[4][4];
#pragma unroll
    for (int i = 0; i < 4; ++i)
#pragma unroll
        for (int j = 0; j < 4; ++j)
#pragma unroll
            for (int r = 0; r < 4; ++r) acc[i][j][r] = 0.f;

    for (int kt = 0; kt < K; kt += 64) {
        __syncthreads();
        {   // stage A (bf16)
            const int r = tid >> 3, c = (tid & 7) << 3;
            const unsigned short* src = A + (size_t)(m0 + r) * K + kt + c;
#pragma unroll
            for (int i = 0; i < 4; ++i) {
                int4 v = *(const int4*)(src + (size_t)i * 32 * K);
                *(int4*)&As[(r + i * 32) * LDP + c] = v;
            }
        }
        {   // stage B from f32, converting
            const int r = tid >> 4, c = (tid & 15) << 2;
            const float* src = B + (size_t)(n0 + r) * K + kt + c;
#pragma unroll
            for (int i = 0; i < 8; ++i) {
                float4 v = *(const float4*)(src + (size_t)i * 16 * K);
                union { unsigned short us[4]; uint2 u2; } t;
                t.us[0] = f2bf(v.x); t.us[1] = f2bf(v.y);
                t.us[2] = f2bf(v.z); t.us[3] = f2bf(v.w);
                *(uint2*)&Bs[(r + i * 16) * LDP + c] = t.u2;
            }
        }
        __syncthreads();
#pragma unroll
        for (int ks = 0; ks < 64; ks += 32) {
            const int col = ks + ((lane >> 4) << 3);
            const int ra = wm + (lane & 15);
            const int rb = wn + (lane & 15);
            bf16x8 af[4], bfr[4];
#pragma unroll
            for (int i = 0; i < 4; ++i)
                af[i] = *(const bf16x8*)&As[(ra + i * 16) * LDP + col];
#pragma unroll
            for (int j = 0; j < 4; ++j)
                bfr[j] = *(const bf16x8*)&Bs[(rb + j * 16) * LDP + col];
#pragma unroll
            for (int i = 0; i < 4; ++i)
#pragma unroll
                for (int j = 0; j < 4; ++j)
                    acc[i][j] = __builtin_amdgcn_mfma_f32_16x16x32_bf16(
                        af[i], bfr[j], acc[i][j], 0, 0, 0);
        }
    }

#pragma unroll
    for (int i = 0; i < 4; ++i) {
#pragma unroll
        for (int r = 0; r < 4; ++r) {
            const int gm = m0 + wm + i * 16 + ((lane >> 4) << 2) + r;
#pragma unroll
            for (int j = 0; j < 4; ++j) {
                const int gn = n0 + wn + j * 16 + (lane & 15);
                out[(size_t)gm * N + gn] = acc[i][j][r] + bias[gn];
            }
        }
    }
}

// ------ att_res[b,h] = sum_s softmax(scores[b])_s * att_feats[b,s,h] --------
__global__ void k_attres_sm(const float* __restrict__ scores,
                            const unsigned short* __restrict__ attf,
                            unsigned short* __restrict__ attres) {
    int b = blockIdx.y;
    int h = blockIdx.x * blockDim.x + threadIdx.x;
    const float* sc = scores + b * Sn;
    float m = -1e30f;
#pragma unroll 7
    for (int s = 0; s < Sn; ++s) m = fmaxf(m, sc[s]);
    float sum = 0.f;
#pragma unroll 7
    for (int s = 0; s < Sn; ++s) sum += __expf(sc[s] - m);
    const float inv = 1.f / sum;
    const unsigned short* p = attf + (size_t)b * Sn * Hn + h;
    float acc = 0.f;
#pragma unroll 7
    for (int s = 0; s < Sn; ++s)
        acc += __expf(sc[s] - m) * bf2f(p[(size_t)s * Hn]);
    attres[(size_t)b * Hn + h] = f2bf(acc * inv);
}

// -------------------- LSTM tail ---------------------------------------------
__global__ void k_final(const float* __restrict__ sums, const float* __restrict__ a2c,
                        const float* __restrict__ state, const int* __restrict__ timep,
                        float* __restrict__ out) {
    int idx = blockIdx.x * blockDim.x + threadIdx.x;  // over B*H
    int b = idx >> 11, h = idx & (Hn - 1);
    const float* srow = sums + (size_t)b * 5 * Hn;
    float ig = 1.f / (1.f + __expf(-srow[h]));
    float fg = 1.f / (1.f + __expf(-srow[Hn + h]));
    float og = 1.f / (1.f + __expf(-srow[2 * Hn + h]));
    float t1 = srow[3 * Hn + h] + a2c[(size_t)b * 2 * Hn + h];
    float t2 = srow[4 * Hn + h] + a2c[(size_t)b * 2 * Hn + Hn + h];
    float intr = fmaxf(t1, t2);
    float cprev = (timep[0] == 0) ? 0.f : state[(size_t)Bn * Hn + idx];  // state[1,0,b,:]
    float c = fg * cprev + ig * intr;
    float hh = og * tanhf(c);
    const int BH = Bn * Hn;
    out[idx] = hh;            // output (B,1,H)
    out[BH + idx] = hh;       // next_h (1,B,H)
    out[2 * BH + idx] = c;    // next_c (1,B,H)
}

// ---------------------------------------------------------------------------
extern "C" void kernel_launch(void* const* d_in, const int* in_sizes, int n_in,
                              void* d_out, int out_size, void* d_ws, size_t ws_size,
                              hipStream_t stream) {
    const float* V        = (const float*)d_in[0];
    const float* state    = (const float*)d_in[2];
    const int*   captions = (const int*)d_in[3];
    const int*   timep    = (const int*)d_in[4];
    const float* att_W    = (const float*)d_in[7];
    const float* att_b    = (const float*)d_in[8];
    const float* emb      = (const float*)d_in[9];
    const float* ctx_W    = (const float*)d_in[10];
    const float* ctx_b    = (const float*)d_in[11];
    const float* a2c_W    = (const float*)d_in[12];
    const float* a2c_b    = (const float*)d_in[13];
    const float* i2h_W    = (const float*)d_in[14];
    const float* i2h_b    = (const float*)d_in[15];
    const float* h2h_W    = (const float*)d_in[16];
    const float* h2h_b    = (const float*)d_in[17];
    const float* h2att_W  = (const float*)d_in[18];
    const float* h2att_b  = (const float*)d_in[19];
    const float* alpha_W  = (const float*)d_in[20];

    // workspace layout (bf16 elems first, then f32)
    unsigned short* Vb      = (unsigned short*)d_ws;        // 25,690,112
    unsigned short* attWb   = Vb + (size_t)Mrows * Hn;      //  4,194,304
    unsigned short* ctxWb   = attWb + (size_t)Hn * Hn;      //  4,194,304
    unsigned short* attfb   = ctxWb + (size_t)Hn * Hn;      // 25,690,112
    unsigned short* xtb     = attfb + (size_t)Mrows * Hn;   //    524,288
    unsigned short* hb      = xtb + Bn * Hn;                //    524,288
    unsigned short* attresb = hb + Bn * Hn;                 //    524,288
    float* atth    = (float*)(attresb + Bn * Hn);           //    524,288 f32
    float* scores  = atth + Bn * Hn;                        //     12,544
    float* weight  = scores + Mrows;                        //     12,544 (unused)
    float* sums    = weight + Mrows;                        //  2,621,440
    float* a2c_out = sums + (size_t)Bn * 5 * Hn;            //  1,048,576

    hipMemsetAsync(scores, 0, Mrows * sizeof(float), stream);

    const int nc0 = Mrows * Hn / 8, nc1 = Hn * Hn / 8, nc2 = Hn * Hn / 8;
    k_convert3<<<(nc0 + nc1 + nc2 + 255) / 256, 256, 0, stream>>>(
        V, Vb, nc0, att_W, attWb, nc1, ctx_W, ctxWb, nc2);
    k_gather<<<Bn, 256, 0, stream>>>(emb, state, captions, timep, xtb, hb);

    const int nwg = (Mrows / 256) * (Hn / 256);   // 49*8 = 392, %8 == 0

    // att_feats = relu(V @ att_W^T + att_b) -> bf16   [8-phase v3, m-band]
    k_gemm8<0><<<nwg, 512, 0, stream>>>(
        Vb, attWb, att_b, attfb, nullptr, nullptr, Mrows, Hn, Hn);
    // fused: sums = xt@i2h^T + h@h2h^T + biases ; atth = h@h2att^T + h2att_b
    k_gemm_pre<<<dim3(96, 2), 256, 0, stream>>>(
        xtb, hb, i2h_W, h2h_W, h2att_W, i2h_b, h2h_b, h2att_b, sums, atth);
    // scores[m] = sum_n tanh(att_feats@ctx_W^T + ctx_b + att_h) * alpha_W
    k_gemm8<3><<<nwg, 512, 0, stream>>>(
        attfb, ctxWb, ctx_b, scores, atth, alpha_W, Mrows, Hn, Hn);
    // att_res with fused row-softmax
    k_attres_sm<<<dim3(Hn / 256, Bn), 256, 0, stream>>>(scores, attfb, attresb);
    // a2c_out = att_res @ a2c_W^T + a2c_b  (f32 out)
    k_gemm_s<<<dim3(2 * Hn / 128, Bn / 128), 256, 0, stream>>>(
        attresb, a2c_W, a2c_b, a2c_out, Bn, 2 * Hn, Hn);

    k_final<<<Bn * Hn / 256, 256, 0, stream>>>(sums, a2c_out, state, timep, (float*)d_out);
}